// Round 2
// baseline (89.842 us; speedup 1.0000x reference)
//
#include <hip/hip_runtime.h>
#include <math.h>

// WildcatPool2d: x[32,64,64,512] fp32 -> out[32,512] fp32
// out[b,c] = mean(top20 over 4096 spatial) + mean(bottom20 over 4096 spatial)
//
// Round 2: software-pipelined register double-buffer (vA/vB). Loads for
// batch t+1 are issued before sorting batch t, so HBM latency (~700cyc)
// hides under the ~1728-cycle sort+merge of the previous batch.

constexpr int CH    = 512;    // channels
constexpr int NROWS = 4096;   // H*W
constexpr int K     = 20;

__device__ __forceinline__ void ce_desc(float& a, float& b) {
  float hi = fmaxf(a, b);
  float lo = fminf(a, b);
  a = hi; b = lo;
}
__device__ __forceinline__ void ce_asc(float& a, float& b) {
  float lo = fminf(a, b);
  float hi = fmaxf(a, b);
  a = lo; b = hi;
}

// full bitonic sort of 32 registers, descending
__device__ __forceinline__ void sort32_desc(float* v) {
  #pragma unroll
  for (int k = 2; k <= 32; k <<= 1) {
    #pragma unroll
    for (int j = k >> 1; j > 0; j >>= 1) {
      #pragma unroll
      for (int i = 0; i < 32; ++i) {
        int l = i ^ j;
        if (l > i) {
          if ((i & k) == 0) ce_desc(v[i], v[l]);
          else              ce_asc(v[i], v[l]);
        }
      }
    }
  }
}

// clean a 32-length bitonic sequence into descending order
__device__ __forceinline__ void clean32_desc(float* v) {
  #pragma unroll
  for (int j = 16; j > 0; j >>= 1) {
    #pragma unroll
    for (int i = 0; i < 32; ++i) {
      int l = i ^ j;
      if (l > i) ce_desc(v[i], v[l]);
    }
  }
}
// clean a 32-length bitonic sequence into ascending order
__device__ __forceinline__ void clean32_asc(float* v) {
  #pragma unroll
  for (int j = 16; j > 0; j >>= 1) {
    #pragma unroll
    for (int i = 0; i < 32; ++i) {
      int l = i ^ j;
      if (l > i) ce_asc(v[i], v[l]);
    }
  }
}

// merge a descending-sorted 32-array d into top (descending, keeps 32 largest)
__device__ __forceinline__ void merge_top(float* top, const float* d) {
  #pragma unroll
  for (int i = 0; i < 32; ++i) top[i] = fmaxf(top[i], d[31 - i]);
  clean32_desc(top);
}
// merge a descending-sorted 32-array d into bot (ascending, keeps 32 smallest)
__device__ __forceinline__ void merge_bot(float* bot, const float* d) {
  #pragma unroll
  for (int i = 0; i < 32; ++i) bot[i] = fminf(bot[i], d[i]);
  clean32_asc(bot);
}

__device__ __forceinline__ void process_batch(float* v, float* top, float* bot) {
  sort32_desc(v);
  merge_top(top, v);
  merge_bot(bot, v);
}

__global__ __launch_bounds__(512)
void wildcat_topk_kernel(const float* __restrict__ x, float* __restrict__ out) {
  const int b     = blockIdx.x >> 4;           // 32 batches
  const int cbase = (blockIdx.x & 15) << 5;    // 16 channel groups of 32
  const int w     = threadIdx.x >> 6;          // wave 0..7
  const int lane  = threadIdx.x & 63;
  const int c     = cbase + (lane & 31);
  const int rpar  = lane >> 5;                 // row parity 0/1

  // wave w owns rows [w*512, w*512+512); lane parity splits even/odd rows
  const float* p0 = x + ((size_t)(b * NROWS + w * 512 + rpar)) * CH + c;

  float top[32], bot[32];
  #pragma unroll
  for (int i = 0; i < 32; ++i) { top[i] = -INFINITY; bot[i] = INFINITY; }

  float vA[32], vB[32];

  // prologue: batch 0 -> vA
  #pragma unroll
  for (int u = 0; u < 32; ++u)
    vA[u] = p0[((size_t)u) * (2 * CH)];

  // 8 batches total, processed in 4 even/odd pairs (loop NOT unrolled to
  // keep the body within I-cache)
  for (int tp = 0; tp < 4; ++tp) {
    // prefetch batch 2tp+1 -> vB (overlaps sort of vA)
    {
      const float* p = p0 + ((size_t)((2 * tp + 1) * 32)) * (2 * CH);
      #pragma unroll
      for (int u = 0; u < 32; ++u)
        vB[u] = p[((size_t)u) * (2 * CH)];
    }
    process_batch(vA, top, bot);   // batch 2tp

    // prefetch batch 2tp+2 -> vA (overlaps sort of vB); skip past the end
    if (tp < 3) {
      const float* p = p0 + ((size_t)((2 * tp + 2) * 32)) * (2 * CH);
      #pragma unroll
      for (int u = 0; u < 32; ++u)
        vA[u] = p[((size_t)u) * (2 * CH)];
    }
    process_batch(vB, top, bot);   // batch 2tp+1
  }

  // --- intra-wave merge: lane l <-> l+32 (same channel, other row parity) ---
  {
    float pt[32], pb[32];
    #pragma unroll
    for (int i = 0; i < 32; ++i) pt[i] = __shfl_xor(top[i], 32, 64);
    #pragma unroll
    for (int i = 0; i < 32; ++i) pb[i] = __shfl_xor(bot[i], 32, 64);
    #pragma unroll
    for (int i = 0; i < 32; ++i) top[i] = fmaxf(top[i], pt[31 - i]);
    clean32_desc(top);
    #pragma unroll
    for (int i = 0; i < 32; ++i) bot[i] = fminf(bot[i], pb[31 - i]);
    clean32_asc(bot);
  }

  // --- cross-wave tree merge via LDS: 8 -> 4 -> 2 -> 1 ---
  __shared__ float lds[4 * 32 * 64];   // 32 KB

  #pragma unroll
  for (int half = 4; half >= 1; half >>= 1) {
    __syncthreads();
    if (w >= half && w < 2 * half && lane < 32) {
      float* dst = &lds[((w - half) * 32 + lane) * 64];
      #pragma unroll
      for (int i = 0; i < 32; ++i) { dst[i] = top[i]; dst[32 + i] = bot[i]; }
    }
    __syncthreads();
    if (w < half && lane < 32) {
      const float* src = &lds[(w * 32 + lane) * 64];
      float pt[32], pb[32];
      #pragma unroll
      for (int i = 0; i < 32; ++i) { pt[i] = src[i]; pb[i] = src[32 + i]; }
      #pragma unroll
      for (int i = 0; i < 32; ++i) top[i] = fmaxf(top[i], pt[31 - i]);
      clean32_desc(top);
      #pragma unroll
      for (int i = 0; i < 32; ++i) bot[i] = fminf(bot[i], pb[31 - i]);
      clean32_asc(bot);
    }
  }

  if (w == 0 && lane < 32) {
    float s = 0.f;
    #pragma unroll
    for (int i = 0; i < K; ++i) s += top[i] + bot[i];
    out[b * CH + cbase + lane] = s * (1.0f / K);
  }
}

extern "C" void kernel_launch(void* const* d_in, const int* in_sizes, int n_in,
                              void* d_out, int out_size, void* d_ws, size_t ws_size,
                              hipStream_t stream) {
  const float* x = (const float*)d_in[0];
  float* out = (float*)d_out;
  // grid: 32 (B) * 16 channel-groups = 512 blocks, 512 threads each
  hipLaunchKernelGGL(wildcat_topk_kernel, dim3(512), dim3(512), 0, stream, x, out);
}

// Round 3
// 72.581 us; speedup vs baseline: 1.2378x; 1.2378x over previous
//
#include <hip/hip_runtime.h>
#include <math.h>

// WildcatPool2d: x[32,64,64,512] fp32 -> out[32,512] fp32
// out[b,c] = mean(top20 over 4096 spatial) + mean(bottom20 over 4096 spatial)
//
// Round 3: fix the round-2 register cliff (VGPR_Count=92 -> arrays demoted).
// 256-thread blocks + __launch_bounds__(256,1) -> 256-VGPR cap, no spill.
// Grid 512 blocks = 2 blocks/CU, all co-resident (no tail). Register
// double-buffer pipeline kept: batch t+1's 32 loads issue ~1700 VALU cycles
// before their use, hiding HBM latency inside a single wave.

constexpr int CH    = 512;    // channels
constexpr int NROWS = 4096;   // H*W
constexpr int K     = 20;

__device__ __forceinline__ void ce_desc(float& a, float& b) {
  float hi = fmaxf(a, b);
  float lo = fminf(a, b);
  a = hi; b = lo;
}
__device__ __forceinline__ void ce_asc(float& a, float& b) {
  float lo = fminf(a, b);
  float hi = fmaxf(a, b);
  a = lo; b = hi;
}

// full bitonic sort of 32 registers, descending
__device__ __forceinline__ void sort32_desc(float* v) {
  #pragma unroll
  for (int k = 2; k <= 32; k <<= 1) {
    #pragma unroll
    for (int j = k >> 1; j > 0; j >>= 1) {
      #pragma unroll
      for (int i = 0; i < 32; ++i) {
        int l = i ^ j;
        if (l > i) {
          if ((i & k) == 0) ce_desc(v[i], v[l]);
          else              ce_asc(v[i], v[l]);
        }
      }
    }
  }
}

// clean a 32-length bitonic sequence into descending order
__device__ __forceinline__ void clean32_desc(float* v) {
  #pragma unroll
  for (int j = 16; j > 0; j >>= 1) {
    #pragma unroll
    for (int i = 0; i < 32; ++i) {
      int l = i ^ j;
      if (l > i) ce_desc(v[i], v[l]);
    }
  }
}
// clean a 32-length bitonic sequence into ascending order
__device__ __forceinline__ void clean32_asc(float* v) {
  #pragma unroll
  for (int j = 16; j > 0; j >>= 1) {
    #pragma unroll
    for (int i = 0; i < 32; ++i) {
      int l = i ^ j;
      if (l > i) ce_asc(v[i], v[l]);
    }
  }
}

// merge a descending-sorted 32-array d into top (descending, keeps 32 largest)
__device__ __forceinline__ void merge_top(float* top, const float* d) {
  #pragma unroll
  for (int i = 0; i < 32; ++i) top[i] = fmaxf(top[i], d[31 - i]);
  clean32_desc(top);
}
// merge a descending-sorted 32-array d into bot (ascending, keeps 32 smallest)
__device__ __forceinline__ void merge_bot(float* bot, const float* d) {
  #pragma unroll
  for (int i = 0; i < 32; ++i) bot[i] = fminf(bot[i], d[i]);
  clean32_asc(bot);
}

__device__ __forceinline__ void process_batch(float* v, float* top, float* bot) {
  sort32_desc(v);
  merge_top(top, v);
  merge_bot(bot, v);
}

// load batch t (32 elems, stride 2 rows) into v
__device__ __forceinline__ void load_batch(const float* __restrict__ p0, int t, float* v) {
  const float* p = p0 + (size_t)t * (64 * CH);
  #pragma unroll
  for (int u = 0; u < 32; ++u)
    v[u] = p[(size_t)(u * 2 * CH)];
}

__global__ __launch_bounds__(256, 1)
void wildcat_topk_kernel(const float* __restrict__ x, float* __restrict__ out) {
  const int b     = blockIdx.x >> 4;           // 32 batches
  const int cbase = (blockIdx.x & 15) << 5;    // 16 channel groups of 32
  const int w     = threadIdx.x >> 6;          // wave 0..3
  const int lane  = threadIdx.x & 63;
  const int c     = cbase + (lane & 31);
  const int rpar  = lane >> 5;                 // row parity 0/1

  // wave w owns rows [w*1024, (w+1)*1024); lane parity splits even/odd rows.
  // thread's batch t element u = row  w*1024 + rpar + (t*32+u)*2
  const float* p0 = x + ((size_t)(b * NROWS + w * 1024 + rpar)) * CH + c;

  float top[32], bot[32], vA[32], vB[32];

  // prologue: batch 0 -> vA, batch 1 -> vB (both in flight)
  load_batch(p0, 0, vA);
  load_batch(p0, 1, vB);

  // batch 0 initializes top/bot directly (saves one merge)
  sort32_desc(vA);
  #pragma unroll
  for (int i = 0; i < 32; ++i) { top[i] = vA[i]; bot[i] = vA[31 - i]; }

  // batches 1..14 in 7 ping-pong pairs; batch 15 in the epilogue.
  for (int tp = 0; tp < 7; ++tp) {
    load_batch(p0, 2 * tp + 2, vA);   // prefetch (overlaps sort of vB)
    process_batch(vB, top, bot);      // batch 2tp+1
    load_batch(p0, 2 * tp + 3, vB);   // prefetch (overlaps sort of vA)
    process_batch(vA, top, bot);      // batch 2tp+2
  }
  process_batch(vB, top, bot);        // batch 15

  // --- intra-wave merge: lane l <-> l+32 (same channel, other row parity) ---
  {
    float pt[32], pb[32];
    #pragma unroll
    for (int i = 0; i < 32; ++i) pt[i] = __shfl_xor(top[i], 32, 64);
    #pragma unroll
    for (int i = 0; i < 32; ++i) pb[i] = __shfl_xor(bot[i], 32, 64);
    #pragma unroll
    for (int i = 0; i < 32; ++i) top[i] = fmaxf(top[i], pt[31 - i]);
    clean32_desc(top);
    #pragma unroll
    for (int i = 0; i < 32; ++i) bot[i] = fminf(bot[i], pb[31 - i]);
    clean32_asc(bot);
  }

  // --- cross-wave tree merge via LDS: 4 -> 2 -> 1 ---
  __shared__ float lds[2 * 32 * 64];   // 16 KB

  #pragma unroll
  for (int half = 2; half >= 1; half >>= 1) {
    __syncthreads();
    if (w >= half && w < 2 * half && lane < 32) {
      float* dst = &lds[((w - half) * 32 + lane) * 64];
      #pragma unroll
      for (int i = 0; i < 32; ++i) { dst[i] = top[i]; dst[32 + i] = bot[i]; }
    }
    __syncthreads();
    if (w < half && lane < 32) {
      const float* src = &lds[(w * 32 + lane) * 64];
      float pt[32], pb[32];
      #pragma unroll
      for (int i = 0; i < 32; ++i) { pt[i] = src[i]; pb[i] = src[32 + i]; }
      #pragma unroll
      for (int i = 0; i < 32; ++i) top[i] = fmaxf(top[i], pt[31 - i]);
      clean32_desc(top);
      #pragma unroll
      for (int i = 0; i < 32; ++i) bot[i] = fminf(bot[i], pb[31 - i]);
      clean32_asc(bot);
    }
  }

  if (w == 0 && lane < 32) {
    float s = 0.f;
    #pragma unroll
    for (int i = 0; i < K; ++i) s += top[i] + bot[i];
    out[b * CH + cbase + lane] = s * (1.0f / K);
  }
}

extern "C" void kernel_launch(void* const* d_in, const int* in_sizes, int n_in,
                              void* d_out, int out_size, void* d_ws, size_t ws_size,
                              hipStream_t stream) {
  const float* x = (const float*)d_in[0];
  float* out = (float*)d_out;
  // grid: 32 (B) * 16 channel-groups = 512 blocks, 256 threads each
  // (2 blocks/CU, all co-resident)
  hipLaunchKernelGGL(wildcat_topk_kernel, dim3(512), dim3(256), 0, stream, x, out);
}

// Round 4
// 70.795 us; speedup vs baseline: 1.2690x; 1.0252x over previous
//
#include <hip/hip_runtime.h>
#include <math.h>

// WildcatPool2d: x[32,64,64,512] fp32 -> out[32,512] fp32
// out[b,c] = mean(top20 over 4096 spatial) + mean(bottom20 over 4096 spatial)
//
// Round 4: round-3 timing matched mem_time + valu_time (43+26 us) exactly ->
// the register ping-pong gave zero overlap; the scheduler sank prefetch
// loads to just before use (to cut register pressure). Pin the issue order
// with __builtin_amdgcn_sched_barrier(0) after each prefetch so the 32
// in-flight loads ride under the ~1960-cycle sort of the in-hand batch
// (counted vmcnt(32) wait, never a drain).

constexpr int CH    = 512;    // channels
constexpr int NROWS = 4096;   // H*W
constexpr int K     = 20;

__device__ __forceinline__ void ce_desc(float& a, float& b) {
  float hi = fmaxf(a, b);
  float lo = fminf(a, b);
  a = hi; b = lo;
}
__device__ __forceinline__ void ce_asc(float& a, float& b) {
  float lo = fminf(a, b);
  float hi = fmaxf(a, b);
  a = lo; b = hi;
}

// full bitonic sort of 32 registers, descending
__device__ __forceinline__ void sort32_desc(float* v) {
  #pragma unroll
  for (int k = 2; k <= 32; k <<= 1) {
    #pragma unroll
    for (int j = k >> 1; j > 0; j >>= 1) {
      #pragma unroll
      for (int i = 0; i < 32; ++i) {
        int l = i ^ j;
        if (l > i) {
          if ((i & k) == 0) ce_desc(v[i], v[l]);
          else              ce_asc(v[i], v[l]);
        }
      }
    }
  }
}

// clean a 32-length bitonic sequence into descending order
__device__ __forceinline__ void clean32_desc(float* v) {
  #pragma unroll
  for (int j = 16; j > 0; j >>= 1) {
    #pragma unroll
    for (int i = 0; i < 32; ++i) {
      int l = i ^ j;
      if (l > i) ce_desc(v[i], v[l]);
    }
  }
}
// clean a 32-length bitonic sequence into ascending order
__device__ __forceinline__ void clean32_asc(float* v) {
  #pragma unroll
  for (int j = 16; j > 0; j >>= 1) {
    #pragma unroll
    for (int i = 0; i < 32; ++i) {
      int l = i ^ j;
      if (l > i) ce_asc(v[i], v[l]);
    }
  }
}

// merge a descending-sorted 32-array d into top (descending, keeps 32 largest)
__device__ __forceinline__ void merge_top(float* top, const float* d) {
  #pragma unroll
  for (int i = 0; i < 32; ++i) top[i] = fmaxf(top[i], d[31 - i]);
  clean32_desc(top);
}
// merge a descending-sorted 32-array d into bot (ascending, keeps 32 smallest)
__device__ __forceinline__ void merge_bot(float* bot, const float* d) {
  #pragma unroll
  for (int i = 0; i < 32; ++i) bot[i] = fminf(bot[i], d[i]);
  clean32_asc(bot);
}

__device__ __forceinline__ void process_batch(float* v, float* top, float* bot) {
  sort32_desc(v);
  merge_top(top, v);
  merge_bot(bot, v);
}

// load batch t (32 elems, stride 2 rows) into v
__device__ __forceinline__ void load_batch(const float* __restrict__ p0, int t, float* v) {
  const float* p = p0 + (size_t)t * (64 * CH);
  #pragma unroll
  for (int u = 0; u < 32; ++u)
    v[u] = p[(size_t)(u * 2 * CH)];
}

__global__ __launch_bounds__(256, 1)
void wildcat_topk_kernel(const float* __restrict__ x, float* __restrict__ out) {
  const int b     = blockIdx.x >> 4;           // 32 batches
  const int cbase = (blockIdx.x & 15) << 5;    // 16 channel groups of 32
  const int w     = threadIdx.x >> 6;          // wave 0..3
  const int lane  = threadIdx.x & 63;
  const int c     = cbase + (lane & 31);
  const int rpar  = lane >> 5;                 // row parity 0/1

  // wave w owns rows [w*1024, (w+1)*1024); lane parity splits even/odd rows.
  const float* p0 = x + ((size_t)(b * NROWS + w * 1024 + rpar)) * CH + c;

  float top[32], bot[32], vA[32], vB[32];

  // prologue: batch 0 -> vA, batch 1 -> vB (both in flight)
  load_batch(p0, 0, vA);
  load_batch(p0, 1, vB);
  __builtin_amdgcn_sched_barrier(0);   // pin: both prefetches issued before any sort

  // batch 0 initializes top/bot directly (saves one merge)
  sort32_desc(vA);
  #pragma unroll
  for (int i = 0; i < 32; ++i) { top[i] = vA[i]; bot[i] = vA[31 - i]; }

  // batches 1..14 in 7 ping-pong pairs; batch 15 in the epilogue.
  for (int tp = 0; tp < 7; ++tp) {
    load_batch(p0, 2 * tp + 2, vA);    // prefetch (must overlap sort of vB)
    __builtin_amdgcn_sched_barrier(0); // loads may not sink below this point
    process_batch(vB, top, bot);       // batch 2tp+1

    load_batch(p0, 2 * tp + 3, vB);    // prefetch (must overlap sort of vA)
    __builtin_amdgcn_sched_barrier(0);
    process_batch(vA, top, bot);       // batch 2tp+2
  }
  process_batch(vB, top, bot);         // batch 15

  // --- intra-wave merge: lane l <-> l+32 (same channel, other row parity) ---
  {
    float pt[32], pb[32];
    #pragma unroll
    for (int i = 0; i < 32; ++i) pt[i] = __shfl_xor(top[i], 32, 64);
    #pragma unroll
    for (int i = 0; i < 32; ++i) pb[i] = __shfl_xor(bot[i], 32, 64);
    #pragma unroll
    for (int i = 0; i < 32; ++i) top[i] = fmaxf(top[i], pt[31 - i]);
    clean32_desc(top);
    #pragma unroll
    for (int i = 0; i < 32; ++i) bot[i] = fminf(bot[i], pb[31 - i]);
    clean32_asc(bot);
  }

  // --- cross-wave tree merge via LDS: 4 -> 2 -> 1 ---
  __shared__ float lds[2 * 32 * 64];   // 16 KB

  #pragma unroll
  for (int half = 2; half >= 1; half >>= 1) {
    __syncthreads();
    if (w >= half && w < 2 * half && lane < 32) {
      float* dst = &lds[((w - half) * 32 + lane) * 64];
      #pragma unroll
      for (int i = 0; i < 32; ++i) { dst[i] = top[i]; dst[32 + i] = bot[i]; }
    }
    __syncthreads();
    if (w < half && lane < 32) {
      const float* src = &lds[(w * 32 + lane) * 64];
      float pt[32], pb[32];
      #pragma unroll
      for (int i = 0; i < 32; ++i) { pt[i] = src[i]; pb[i] = src[32 + i]; }
      #pragma unroll
      for (int i = 0; i < 32; ++i) top[i] = fmaxf(top[i], pt[31 - i]);
      clean32_desc(top);
      #pragma unroll
      for (int i = 0; i < 32; ++i) bot[i] = fminf(bot[i], pb[31 - i]);
      clean32_asc(bot);
    }
  }

  if (w == 0 && lane < 32) {
    float s = 0.f;
    #pragma unroll
    for (int i = 0; i < K; ++i) s += top[i] + bot[i];
    out[b * CH + cbase + lane] = s * (1.0f / K);
  }
}

extern "C" void kernel_launch(void* const* d_in, const int* in_sizes, int n_in,
                              void* d_out, int out_size, void* d_ws, size_t ws_size,
                              hipStream_t stream) {
  const float* x = (const float*)d_in[0];
  float* out = (float*)d_out;
  // grid: 32 (B) * 16 channel-groups = 512 blocks, 256 threads each
  // (2 blocks/CU, all co-resident)
  hipLaunchKernelGGL(wildcat_topk_kernel, dim3(512), dim3(256), 0, stream, x, out);
}